// Round 5
// baseline (421.450 us; speedup 1.0000x reference)
//
#include <hip/hip_runtime.h>

// Problem constants
#define T_LEN 4096
#define DMODEL 512
#define DIM 512
#define NBATCH 8
#define MROWS (NBATCH * T_LEN)   // 32768
#define NCHUNK 64
#define LCHUNK 64                 // T_LEN / NCHUNK

typedef __attribute__((ext_vector_type(8))) short short8;
typedef __attribute__((ext_vector_type(4))) float float4v;

__device__ __forceinline__ ushort f2b(float f) {
    union { float fl; unsigned u; } v; v.fl = f;
    unsigned u = v.u;
    return (ushort)((u + 0x7FFFu + ((u >> 16) & 1u)) >> 16);
}
__device__ __forceinline__ float b2f(ushort u) {
    union { unsigned u; float f; } v; v.u = (unsigned)u << 16; return v.f;
}
// bf16 pair unpack from a packed uint (lo = element 2k, hi = element 2k+1)
__device__ __forceinline__ float bflo(unsigned u) {
    union { unsigned x; float f; } v; v.x = u << 16; return v.f;
}
__device__ __forceinline__ float bfhi(unsigned u) {
    union { unsigned x; float f; } v; v.x = u & 0xffff0000u; return v.f;
}

__device__ __forceinline__ void glds16(const ushort* g, ushort* l) {
    __builtin_amdgcn_global_load_lds(
        (const __attribute__((address_space(1))) void*)g,
        (__attribute__((address_space(3))) void*)l, 16, 0, 0);
}

// ---------------- merged prep kernel ----------------
// blocks [0, NBX)            : x fp32 -> bf16
// blocks [NBX, NBX+2048)     : BT build
// blocks [NBX+2048, +2048)   : CT build
#define NBX (MROWS * 512 / 4 / 256)
__global__ __launch_bounds__(256) void k_prep(const float* __restrict__ x,
                                              const float* __restrict__ Bre,
                                              const float* __restrict__ Bim,
                                              const float* __restrict__ gamma_log,
                                              const float* __restrict__ Cre,
                                              const float* __restrict__ Cim,
                                              ushort* __restrict__ xb,
                                              ushort* __restrict__ BT,
                                              ushort* __restrict__ CT) {
    int blk = blockIdx.x;
    if (blk < NBX) {
        int i = (blk * 256 + threadIdx.x) * 4;
        float4 v = *(const float4*)(x + i);
        ushort4 o;
        o.x = f2b(v.x); o.y = f2b(v.y); o.z = f2b(v.z); o.w = f2b(v.w);
        *(ushort4*)(xb + i) = o;
    } else if (blk < NBX + 2048) {
        int idx = (blk - NBX) * 256 + threadIdx.x;   // 0 .. 1024*512-1
        int n = idx >> 9;
        int d = idx & 511;
        float v;
        if (n < 512) v = Bre[d * 512 + n] * __expf(gamma_log[n]);
        else { int nn = n - 512; v = Bim[d * 512 + nn] * __expf(gamma_log[nn]); }
        BT[idx] = f2b(v);
    } else {
        int idx = (blk - NBX - 2048) * 256 + threadIdx.x;   // 0 .. 512*1024-1
        int d = idx >> 10;
        int k = idx & 1023;
        float v = (k < 512) ? Cre[k * 512 + d] : -Cim[(k - 512) * 512 + d];
        CT[idx] = f2b(v);
    }
}

// ---------------- bf16 MFMA GEMM: A (MxK rm) * Bt^T (Bt NxK rm) ----------------
// BM=BN=128, BK=64, 256 thr = 4 waves 2x2, wave = 64x64 via 4x4 MFMA 16x16x32 (x2 k-steps).
// glds16 staging; XOR chunk swizzle kills ds_read_b128 bank conflicts (verified R4: 0).
// XCD-aware 1-D remap (round-robin L%8, verified R4: FETCH 166->74MB).
// MODE 1: outputs n-major bf16 planes (oRe/oIm [n][MROWS]) via packed 8B stores.
// MODE 2: y = acc + D*x, row-major fp32.
template<int K, int MODE, int NBN>
__global__ __launch_bounds__(256) void k_gemm(
    const ushort* __restrict__ A, const ushort* __restrict__ Bt,
    ushort* __restrict__ oRe, ushort* __restrict__ oIm,
    float* __restrict__ y, const float* __restrict__ x, const float* __restrict__ Dp) {
    __shared__ ushort sA[128 * 64];
    __shared__ ushort sB[128 * 64];
    const int tid = threadIdx.x;
    const int L = blockIdx.x;
    const int xcd = L & 7;
    const int slot = L >> 3;
    const int m0 = (xcd * 32 + slot / NBN) * 128;
    const int n0 = (slot % NBN) * 128;
    const int wave = tid >> 6;
    const int lane = tid & 63;
    const int wm = (wave >> 1) * 64;
    const int wn = (wave & 1) * 64;
    const int lr = lane & 15;
    const int quad = lane >> 4;

    const int srow = lane >> 3;                 // 0..7 within 8-row group
    const int schunk = (lane & 7) ^ srow;       // XOR swizzle key = row&7
    const ushort* gA0 = A + (size_t)(m0 + wave * 32 + srow) * K + schunk * 8;
    const ushort* gB0 = Bt + (size_t)(n0 + wave * 32 + srow) * K + schunk * 8;

    float4v acc[4][4];
#pragma unroll
    for (int i = 0; i < 4; i++)
#pragma unroll
        for (int j = 0; j < 4; j++) {
            float4v z = {0.f, 0.f, 0.f, 0.f};
            acc[i][j] = z;
        }

    for (int k0 = 0; k0 < K; k0 += 64) {
        __syncthreads();
#pragma unroll
        for (int c = 0; c < 4; c++) {
            glds16(gA0 + (size_t)(c * 8) * K + k0, &sA[(wave * 32 + c * 8) * 64]);
            glds16(gB0 + (size_t)(c * 8) * K + k0, &sB[(wave * 32 + c * 8) * 64]);
        }
        __syncthreads();

#pragma unroll
        for (int kk = 0; kk < 2; kk++) {
            short8 af[4], bfr[4];
#pragma unroll
            for (int i = 0; i < 4; i++) {
                int row = wm + i * 16 + lr;
                af[i] = *(const short8*)&sA[row * 64 + (((kk * 4 + quad) ^ (row & 7)) * 8)];
            }
#pragma unroll
            for (int j = 0; j < 4; j++) {
                int row = wn + j * 16 + lr;
                bfr[j] = *(const short8*)&sB[row * 64 + (((kk * 4 + quad) ^ (row & 7)) * 8)];
            }
#pragma unroll
            for (int i = 0; i < 4; i++)
#pragma unroll
                for (int j = 0; j < 4; j++)
                    acc[i][j] = __builtin_amdgcn_mfma_f32_16x16x32_bf16(af[i], bfr[j], acc[i][j], 0, 0, 0);
        }
    }

    // epilogue: C frag: col = lane&15, row = quad*4 + r (4 consecutive m per lane)
#pragma unroll
    for (int i = 0; i < 4; i++) {
#pragma unroll
        for (int j = 0; j < 4; j++) {
            int m = m0 + wm + i * 16 + quad * 4;
            int gn = n0 + wn + j * 16 + lr;
            if (MODE == 1) {
                // n-major: 4 consecutive m in one lane -> one 8B packed store
                ushort4 h;
                h.x = f2b(acc[i][j][0]); h.y = f2b(acc[i][j][1]);
                h.z = f2b(acc[i][j][2]); h.w = f2b(acc[i][j][3]);
                ushort* dst = (gn < 512) ? (oRe + (size_t)gn * MROWS + m)
                                         : (oIm + (size_t)(gn - 512) * MROWS + m);
                *(ushort4*)dst = h;
            } else {
#pragma unroll
                for (int r = 0; r < 4; r++) {
                    size_t o = (size_t)(m + r) * 512 + gn;
                    y[o] = acc[i][j][r] + Dp[gn] * x[o];
                }
            }
        }
    }
}

// ---------------- scan kernels ----------------
// Bu is n-major: Bu[ch][m], m = b*T_LEN + t. Each lane streams contiguous m.

__device__ __forceinline__ void lambda_of(const float* nu_log, const float* theta_log,
                                          int n, float& lre, float& lim) {
    float e = __expf(nu_log[n]);
    float th = __expf(theta_log[n]);
    float rad = __expf(-e);
    float s, c;
    __sincosf(th, &s, &c);
    lre = rad * c;
    lim = rad * s;
}

// phase 1: per (b, chunk) local scan from zero; 256 threads x 2 channels, per-lane m-stream
__global__ __launch_bounds__(256) void k_scan1(const ushort* __restrict__ BuRe,
                                               const ushort* __restrict__ BuIm,
                                               const float* __restrict__ nu_log,
                                               const float* __restrict__ theta_log,
                                               float* __restrict__ cRe, float* __restrict__ cIm) {
    int n2 = threadIdx.x;
    int b = blockIdx.x >> 6;
    int c = blockIdx.x & 63;
    int ch0 = 2 * n2, ch1 = 2 * n2 + 1;
    float lre0, lim0, lre1, lim1;
    lambda_of(nu_log, theta_log, ch0, lre0, lim0);
    lambda_of(nu_log, theta_log, ch1, lre1, lim1);
    size_t mb = (size_t)b * T_LEN + (size_t)c * LCHUNK;
    const ushort* p0r = BuRe + (size_t)ch0 * MROWS + mb;
    const ushort* p1r = BuRe + (size_t)ch1 * MROWS + mb;
    const ushort* p0i = BuIm + (size_t)ch0 * MROWS + mb;
    const ushort* p1i = BuIm + (size_t)ch1 * MROWS + mb;
    float hr0 = 0.f, hi0 = 0.f, hr1 = 0.f, hi1 = 0.f;
    for (int g = 0; g < LCHUNK / 8; g++) {
        uint4 r0 = *(const uint4*)(p0r + g * 8);
        uint4 i0 = *(const uint4*)(p0i + g * 8);
        uint4 r1 = *(const uint4*)(p1r + g * 8);
        uint4 i1 = *(const uint4*)(p1i + g * 8);
        unsigned rw0[4] = {r0.x, r0.y, r0.z, r0.w};
        unsigned iw0[4] = {i0.x, i0.y, i0.z, i0.w};
        unsigned rw1[4] = {r1.x, r1.y, r1.z, r1.w};
        unsigned iw1[4] = {i1.x, i1.y, i1.z, i1.w};
#pragma unroll
        for (int q = 0; q < 4; q++) {
            float br, bi, nr, ni;
            br = bflo(rw0[q]); bi = bflo(iw0[q]);
            nr = lre0 * hr0 - lim0 * hi0 + br; ni = lre0 * hi0 + lim0 * hr0 + bi;
            hr0 = nr; hi0 = ni;
            br = bfhi(rw0[q]); bi = bfhi(iw0[q]);
            nr = lre0 * hr0 - lim0 * hi0 + br; ni = lre0 * hi0 + lim0 * hr0 + bi;
            hr0 = nr; hi0 = ni;
            br = bflo(rw1[q]); bi = bflo(iw1[q]);
            nr = lre1 * hr1 - lim1 * hi1 + br; ni = lre1 * hi1 + lim1 * hr1 + bi;
            hr1 = nr; hi1 = ni;
            br = bfhi(rw1[q]); bi = bfhi(iw1[q]);
            nr = lre1 * hr1 - lim1 * hi1 + br; ni = lre1 * hi1 + lim1 * hr1 + bi;
            hr1 = nr; hi1 = ni;
        }
    }
    size_t co = ((size_t)b * NCHUNK + c) * 512 + 2 * n2;
    *(float2*)(cRe + co) = make_float2(hr0, hr1);
    *(float2*)(cIm + co) = make_float2(hi0, hi1);
}

// phase 2: combine carries across chunks (serial, 64 iters); 64-thread blocks
__global__ __launch_bounds__(64) void k_scan2(const float* __restrict__ cRe,
                                              const float* __restrict__ cIm,
                                              const float* __restrict__ h0,
                                              const float* __restrict__ nu_log,
                                              const float* __restrict__ theta_log,
                                              float* __restrict__ pRe, float* __restrict__ pIm,
                                              float* __restrict__ newH, int newh_mode) {
    int idx = blockIdx.x * 64 + threadIdx.x;   // 0..4095
    int b = idx >> 9;
    int n = idx & 511;
    float lre, lim;
    lambda_of(nu_log, theta_log, n, lre, lim);
    // lambda^LCHUNK via 6 squarings (LCHUNK = 64)
    float Lr = lre, Li = lim;
#pragma unroll
    for (int s = 0; s < 6; s++) {
        float nr = Lr * Lr - Li * Li;
        float ni = 2.f * Lr * Li;
        Lr = nr; Li = ni;
    }
    float cr = h0[b * 512 + n];
    float ci = 0.f;
#pragma unroll 4
    for (int c = 0; c < NCHUNK; c++) {
        size_t o = ((size_t)b * NCHUNK + c) * 512 + n;
        pRe[o] = cr;
        pIm[o] = ci;
        float ar = cRe[o], ai = cIm[o];
        float nr = Lr * cr - Li * ci + ar;
        float ni = Lr * ci + Li * cr + ai;
        cr = nr; ci = ni;
    }
    size_t ci_idx = (size_t)b * 512 + n;
    if (newh_mode == 1) {
        newH[ci_idx] = cr;
        newH[(size_t)NBATCH * 512 + ci_idx] = ci;
    } else if (newh_mode == 2) {
        newH[ci_idx] = cr;
    } else {
        newH[ci_idx * 2] = cr;
        newH[ci_idx * 2 + 1] = ci;
    }
}

// phase 3: recompute local scan + lambda^{j+1}*entering, write H bf16 [re|im] m-major rows
__global__ __launch_bounds__(256) void k_scan3(const ushort* __restrict__ BuRe,
                                               const ushort* __restrict__ BuIm,
                                               const float* __restrict__ pRe,
                                               const float* __restrict__ pIm,
                                               const float* __restrict__ nu_log,
                                               const float* __restrict__ theta_log,
                                               ushort* __restrict__ Hbf) {
    int n2 = threadIdx.x;
    int b = blockIdx.x >> 6;
    int c = blockIdx.x & 63;
    int ch0 = 2 * n2, ch1 = 2 * n2 + 1;
    float lre0, lim0, lre1, lim1;
    lambda_of(nu_log, theta_log, ch0, lre0, lim0);
    lambda_of(nu_log, theta_log, ch1, lre1, lim1);
    size_t co = ((size_t)b * NCHUNK + c) * 512 + 2 * n2;
    float2 frv = *(const float2*)(pRe + co);
    float2 fiv = *(const float2*)(pIm + co);
    float fr0 = frv.x, fr1 = frv.y, fi0 = fiv.x, fi1 = fiv.y;
    float pr0 = lre0, pi0 = lim0, pr1 = lre1, pi1 = lim1;   // lambda^{j+1}
    float hr0 = 0.f, hi0 = 0.f, hr1 = 0.f, hi1 = 0.f;
    size_t mb = (size_t)b * T_LEN + (size_t)c * LCHUNK;
    const ushort* p0r = BuRe + (size_t)ch0 * MROWS + mb;
    const ushort* p1r = BuRe + (size_t)ch1 * MROWS + mb;
    const ushort* p0i = BuIm + (size_t)ch0 * MROWS + mb;
    const ushort* p1i = BuIm + (size_t)ch1 * MROWS + mb;
    for (int g = 0; g < LCHUNK / 8; g++) {
        uint4 r0 = *(const uint4*)(p0r + g * 8);
        uint4 i0 = *(const uint4*)(p0i + g * 8);
        uint4 r1 = *(const uint4*)(p1r + g * 8);
        uint4 i1 = *(const uint4*)(p1i + g * 8);
        unsigned rw0[4] = {r0.x, r0.y, r0.z, r0.w};
        unsigned iw0[4] = {i0.x, i0.y, i0.z, i0.w};
        unsigned rw1[4] = {r1.x, r1.y, r1.z, r1.w};
        unsigned iw1[4] = {i1.x, i1.y, i1.z, i1.w};
#pragma unroll
        for (int q = 0; q < 4; q++) {
#pragma unroll
            for (int hlf = 0; hlf < 2; hlf++) {
                float br0 = hlf ? bfhi(rw0[q]) : bflo(rw0[q]);
                float bi0 = hlf ? bfhi(iw0[q]) : bflo(iw0[q]);
                float br1 = hlf ? bfhi(rw1[q]) : bflo(rw1[q]);
                float bi1 = hlf ? bfhi(iw1[q]) : bflo(iw1[q]);
                float nr0 = lre0 * hr0 - lim0 * hi0 + br0;
                float ni0 = lre0 * hi0 + lim0 * hr0 + bi0;
                hr0 = nr0; hi0 = ni0;
                float nr1 = lre1 * hr1 - lim1 * hi1 + br1;
                float ni1 = lre1 * hi1 + lim1 * hr1 + bi1;
                hr1 = nr1; hi1 = ni1;
                float vr0 = hr0 + pr0 * fr0 - pi0 * fi0;
                float vi0 = hi0 + pr0 * fi0 + pi0 * fr0;
                float vr1 = hr1 + pr1 * fr1 - pi1 * fi1;
                float vi1 = hi1 + pr1 * fi1 + pi1 * fr1;
                int j = g * 8 + q * 2 + hlf;
                size_t hrow = (mb + j) * 1024;
                ushort2 wre, wim;
                wre.x = f2b(vr0); wre.y = f2b(vr1);
                wim.x = f2b(vi0); wim.y = f2b(vi1);
                *(ushort2*)(Hbf + hrow + 2 * n2) = wre;
                *(ushort2*)(Hbf + hrow + 512 + 2 * n2) = wim;
                float npr0 = pr0 * lre0 - pi0 * lim0;
                float npi0 = pr0 * lim0 + pi0 * lre0;
                pr0 = npr0; pi0 = npi0;
                float npr1 = pr1 * lre1 - pi1 * lim1;
                float npi1 = pr1 * lim1 + pi1 * lre1;
                pr1 = npr1; pi1 = npi1;
            }
        }
    }
}

// ---------------- launch ----------------

extern "C" void kernel_launch(void* const* d_in, const int* in_sizes, int n_in,
                              void* d_out, int out_size, void* d_ws, size_t ws_size,
                              hipStream_t stream) {
    const float* x         = (const float*)d_in[0];
    const float* h0        = (const float*)d_in[1];
    const float* nu_log    = (const float*)d_in[2];
    const float* theta_log = (const float*)d_in[3];
    const float* B_re      = (const float*)d_in[4];
    const float* B_im      = (const float*)d_in[5];
    const float* C_re      = (const float*)d_in[6];
    const float* C_im      = (const float*)d_in[7];
    const float* D_param   = (const float*)d_in[8];
    const float* gamma_log = (const float*)d_in[9];

    char* ws = (char*)d_ws;
    size_t off = 0;
    ushort* Xb   = (ushort*)(ws + off); off += (size_t)MROWS * 512 * 2;
    ushort* BT   = (ushort*)(ws + off); off += (size_t)1024 * 512 * 2;
    ushort* CT   = (ushort*)(ws + off); off += (size_t)512 * 1024 * 2;
    ushort* BuRe = (ushort*)(ws + off); off += (size_t)MROWS * 512 * 2;   // n-major [512][MROWS]
    ushort* BuIm = (ushort*)(ws + off); off += (size_t)MROWS * 512 * 2;
    ushort* Hbf  = (ushort*)(ws + off); off += (size_t)MROWS * 1024 * 2;
    float*  cRe  = (float*)(ws + off); off += (size_t)NBATCH * NCHUNK * 512 * 4;
    float*  cIm  = (float*)(ws + off); off += (size_t)NBATCH * NCHUNK * 512 * 4;
    float*  pRe  = (float*)(ws + off); off += (size_t)NBATCH * NCHUNK * 512 * 4;
    float*  pIm  = (float*)(ws + off); off += (size_t)NBATCH * NCHUNK * 512 * 4;

    float* y_out = (float*)d_out;
    float* newH  = (float*)d_out + (size_t)MROWS * 512;

    const int tail = out_size - MROWS * 512;
    int newh_mode = 0;
    if (tail == NBATCH * 512 * 2) newh_mode = 1;       // planar [re|im] (validated R2)
    else if (tail == NBATCH * 512) newh_mode = 2;

    // merged prep
    k_prep<<<dim3(NBX + 4096), dim3(256), 0, stream>>>(x, B_re, B_im, gamma_log, C_re, C_im,
                                                       Xb, BT, CT);

    // GEMM1: Bu(bf16 n-major planes) = Xb (32768x512) * BT^T (512x1024); 2048 blocks
    k_gemm<512, 1, 8><<<dim3(2048), dim3(256), 0, stream>>>(
        Xb, BT, BuRe, BuIm, nullptr, nullptr, nullptr);

    // scan
    k_scan1<<<dim3(NBATCH * NCHUNK), dim3(256), 0, stream>>>(BuRe, BuIm, nu_log, theta_log, cRe, cIm);
    k_scan2<<<dim3(NBATCH * 512 / 64), dim3(64), 0, stream>>>(cRe, cIm, h0, nu_log, theta_log, pRe, pIm, newH, newh_mode);
    k_scan3<<<dim3(NBATCH * NCHUNK), dim3(256), 0, stream>>>(BuRe, BuIm, pRe, pIm, nu_log, theta_log, Hbf);

    // GEMM2: y = Hbf (32768x1024) * CT^T (1024x512) + D*x; 1024 blocks
    k_gemm<1024, 2, 4><<<dim3(1024), dim3(256), 0, stream>>>(
        Hbf, CT, nullptr, nullptr, y_out, x, D_param);
}